// Round 11
// baseline (336.707 us; speedup 1.0000x reference)
//
#include <hip/hip_runtime.h>
#include <math.h>

#define MEM 128
#define HSTR 136   // LDS row stride for h (bf16 elems): 272B, 16B-aligned, bank-balanced
#define LOG2E 1.4426950408889634f

typedef __bf16 bf16x8 __attribute__((ext_vector_type(8)));
typedef float  f32x4  __attribute__((ext_vector_type(4)));

__device__ __forceinline__ float fast_rcp(float x) { return __builtin_amdgcn_rcpf(x); }
__device__ __forceinline__ float fast_exp2(float x) { return __builtin_amdgcn_exp2f(x); }
__device__ __forceinline__ float fast_sigmoid(float x) {
    return fast_rcp(1.0f + fast_exp2(-LOG2E * x));
}
__device__ __forceinline__ float fast_tanh(float x) {
    return 2.0f * fast_rcp(1.0f + fast_exp2(-2.0f * LOG2E * x)) - 1.0f;
}

// ============ fused: per-thread prep + 128-step LSTM + partial reduce ============
// v9: 512 blocks, overlapping 16-row windows at stride 8 (each row covered by exactly
// 2 blocks, contributions scaled 0.5 -> bitwise-identical, sum exact). Gives 2
// independent barrier domains per CU so one block's compute fills the other's
// barrier/latency stalls. launch_bounds(512,4) = 4 waves/EU = 2 blocks/CU.
// Gate math: 5 exp2 + 2 rcp (merged triple-product reciprocal).
__global__ __launch_bounds__(512, 4) void lstm_kernel(
        const float* __restrict__ numbers, const float* __restrict__ w_num,
        const float* __restrict__ b_num,   const float* __restrict__ W_ih,
        const float* __restrict__ W_hh,    const float* __restrict__ b_ih,
        const float* __restrict__ b_hh,    const float* __restrict__ W_fh,
        const float* __restrict__ b_fh,
        float* __restrict__ fc_sum, float* __restrict__ hs_bar) {
    __shared__ unsigned short hbuf[2][16 * HSTR];   // h state, bf16, [row][col]
    __shared__ float xls[128 * 16];                 // normalized x, [t][row]
    __shared__ float mean_l[100], inv_l[100];

    const int tid  = threadIdx.x;
    const int lane = tid & 63;
    const int wave = tid >> 6;        // 0..7 -> gate-column group
    const int quad = lane >> 4;       // 0..3
    const int lcol = lane & 15;
    const int m0   = wave * 16;       // column offset within a gate (0..112)
    const int r0   = blockIdx.x * 8;  // overlapping window: rows r0..r0+15 (mod 4096)

    // ---- stats LUT (redundant per block, register/LDS only) ----
    if (tid < 100) xls[tid] = numbers[tid];   // stage first 100 numbers
    __syncthreads();
    if (tid < 100) {
        float s = 0.f, ss = 0.f;
        for (int j = 0; j <= tid; ++j) { float v = xls[j]; s += v; ss += v * v; }
        float cap  = (float)(tid + 1);
        float mean = s / cap;
        float var  = ss / cap - mean * mean;
        if (var < 0.f) var = 0.f;
        float sd = sqrtf(var);
        float inv = (cap > 3.0f && sd > 1e-8f) ? (1.0f / sd) : 1.0f;
        mean_l[tid] = mean;
        inv_l[tid]  = inv;
    }
    __syncthreads();

    // gate pre-scales: sigmoid gates -log2e, tanh gate -2*log2e, folded into weights
    const float GS[4] = { -LOG2E, -LOG2E, -2.0f * LOG2E, -LOG2E };

    // ---- per-thread rank-1 coefficients via quad-split dots (no LDS, no barrier) ----
    float ag[4], bg[4];
    #pragma unroll
    for (int g = 0; g < 4; ++g) {
        int j = g * 128 + m0 + lcol;
        const float* row = W_ih + j * 256 + 128 + quad * 32;
        const float* wn  = w_num + quad * 32;
        const float* bn  = b_num + quad * 32;
        float a = 0.f, b = 0.f;
        #pragma unroll
        for (int m = 0; m < 32; m += 4) {
            f32x4 w  = *(const f32x4*)(row + m);
            f32x4 vn = *(const f32x4*)(wn + m);
            f32x4 vb = *(const f32x4*)(bn + m);
            a += w[0] * vn[0] + w[1] * vn[1] + w[2] * vn[2] + w[3] * vn[3];
            b += w[0] * vb[0] + w[1] * vb[1] + w[2] * vb[2] + w[3] * vb[3];
        }
        a += __shfl_xor(a, 16); a += __shfl_xor(a, 32);
        b += __shfl_xor(b, 16); b += __shfl_xor(b, 32);
        ag[g] = a * GS[g];
        bg[g] = (b + b_ih[j] + b_hh[j]) * GS[g];
    }

    // ---- load + normalize x into LDS [t][row] (rows wrap mod 4096) ----
    for (int i = tid; i < 16 * 128; i += 512) {
        int row = i >> 7;
        int t   = i & 127;
        int flat = (((r0 + row) & 4095) * 128) + t;
        int ii = (flat < 100) ? flat : 99;   // k>100 uses stats at k=100
        float v = numbers[flat];
        xls[t * 16 + row] = (v - mean_l[ii]) * inv_l[ii];
    }
    // ---- zero h buffer 0 (h0 = 0) ----
    for (int i = tid; i < 16 * HSTR; i += 512) hbuf[0][i] = 0;

    // ---- persistent W_hh B-fragments (bf16, pre-scaled) in registers: [gate][kk] ----
    bf16x8 bf[4][4];
    #pragma unroll
    for (int g = 0; g < 4; ++g) {
        #pragma unroll
        for (int kk = 0; kk < 4; ++kk) {
            int j = g * 128 + m0 + lcol;            // gate output column (n)
            const float* p = W_hh + j * 128 + kk * 32 + quad * 8;
            f32x4 w0 = *(const f32x4*)p;
            f32x4 w1 = *(const f32x4*)(p + 4);
            bf16x8 bt;
            #pragma unroll
            for (int q = 0; q < 4; ++q) {
                bt[q]     = (__bf16)(w0[q] * GS[g]);
                bt[q + 4] = (__bf16)(w1[q] * GS[g]);
            }
            bf[g][kk] = bt;
        }
    }

    float c[4]  = {0.f, 0.f, 0.f, 0.f};  // C-layout: row = quad*4+r, col = m0+lcol
    float hf[4] = {0.f, 0.f, 0.f, 0.f};
    __syncthreads();

    // ---------------- 128-step LSTM ----------------
    auto step = [&](int t, const unsigned short* hin, unsigned short* hout) {
        bf16x8 af[4];
        #pragma unroll
        for (int kk = 0; kk < 4; ++kk)
            af[kk] = *(const bf16x8*)(const void*)(hin + lcol * HSTR + kk * 32 + quad * 8);
        f32x4 xq = *(const f32x4*)(const void*)(xls + t * 16 + quad * 4);
        f32x4 acc[4];
        #pragma unroll
        for (int g = 0; g < 4; ++g) {
            f32x4 a0;
            #pragma unroll
            for (int r = 0; r < 4; ++r) a0[r] = xq[r] * ag[g] + bg[g];
            #pragma unroll
            for (int kk = 0; kk < 4; ++kk)
                a0 = __builtin_amdgcn_mfma_f32_16x16x32_bf16(af[kk], bf[g][kk], a0, 0, 0, 0);
            acc[g] = a0;
        }
        // gate math (5 exp2 + 2 rcp): acc0/1/3 = -log2e*(i,f,o); acc2 = -2log2e*g
        // c2 = [c*(1+ei)(1+eg) + (1-eg)(1+ef)] / [(1+ef)(1+ei)(1+eg)]
        // h  = (1-ec)/((1+eo)(1+ec)),  ec = 2^(-2*log2e*c2)
        #pragma unroll
        for (int r = 0; r < 4; ++r) {
            float ei = fast_exp2(acc[0][r]);
            float ef = fast_exp2(acc[1][r]);
            float eg = fast_exp2(acc[2][r]);
            float eo = fast_exp2(acc[3][r]);
            float p  = (1.0f + ei) * (1.0f + eg);
            float df = 1.0f + ef;
            float rq = fast_rcp(df * p);
            float c2 = (c[r] * p + (1.0f - eg) * df) * rq;
            c[r] = c2;
            float ec  = fast_exp2(-2.0f * LOG2E * c2);
            float roc = fast_rcp((1.0f + eo) * (1.0f + ec));
            float h   = (1.0f - ec) * roc;                      // so*tanh(c2)
            hf[r] = h;
            hout[(quad * 4 + r) * HSTR + m0 + lcol] = __builtin_bit_cast(unsigned short, (__bf16)h);
        }
        __syncthreads();
    };

    for (int t = 0; t < 128; t += 2) {
        step(t,     hbuf[0], hbuf[1]);
        step(t + 1, hbuf[1], hbuf[0]);
    }
    // final h (t=127) lives in hbuf[0]; final c in regs; hf = final h (fp32)

    // ---- hs_bar partial (x0.5: each row is covered by exactly 2 blocks) ----
    float v = hf[0] + hf[1] + hf[2] + hf[3];
    v += __shfl_xor(v, 16);
    v += __shfl_xor(v, 32);
    if (lane < 16) atomicAdd(&hs_bar[m0 + lane], 0.5f * v);

    // ---- f_g = sigmoid(h @ W_fh^T + b_fh); fc partial = sum_rows f_g*c ----
    f32x4 facc;
    {
        float bb = b_fh[m0 + lcol];
        #pragma unroll
        for (int r = 0; r < 4; ++r) facc[r] = bb;
    }
    #pragma unroll
    for (int kk = 0; kk < 4; ++kk) {
        bf16x8 afr = *(const bf16x8*)(const void*)(hbuf[0] + lcol * HSTR + kk * 32 + quad * 8);
        const float* p = W_fh + (m0 + lcol) * 128 + kk * 32 + quad * 8;
        f32x4 w0 = *(const f32x4*)p;
        f32x4 w1 = *(const f32x4*)(p + 4);
        bf16x8 wt;
        #pragma unroll
        for (int q = 0; q < 4; ++q) { wt[q] = (__bf16)w0[q]; wt[q + 4] = (__bf16)w1[q]; }
        facc = __builtin_amdgcn_mfma_f32_16x16x32_bf16(afr, wt, facc, 0, 0, 0);
    }
    float fcv = 0.f;
    #pragma unroll
    for (int r = 0; r < 4; ++r) fcv += fast_sigmoid(facc[r]) * c[r];
    fcv += __shfl_xor(fcv, 16);
    fcv += __shfl_xor(fcv, 32);
    if (lane < 16) atomicAdd(&fc_sum[m0 + lane], 0.5f * fcv);
}

// ---------------- epilogue: root Tree-LSTM cell + output projection ----------------
__global__ void finalize_kernel(const float* __restrict__ fc_sum,
                                const float* __restrict__ hs_bar,
                                const float* __restrict__ W_iouh,
                                const float* __restrict__ b_iouh,
                                const float* __restrict__ W_lout,
                                const float* __restrict__ b_lout,
                                float* __restrict__ out) {
    __shared__ float hsb[128], iou[384], hfin[128];
    int tid = threadIdx.x;            // 512
    const int part = tid & 3;         // 0..3
    const int jb   = tid >> 2;        // 0..127
    if (tid < 128) hsb[tid] = hs_bar[tid];
    __syncthreads();
    #pragma unroll
    for (int round = 0; round < 3; ++round) {
        int j = jb + round * 128;
        const float* row = W_iouh + j * 128 + part * 32;
        const float* hv  = hsb + part * 32;
        float s = 0.f;
        #pragma unroll
        for (int m = 0; m < 32; m += 4) {
            f32x4 w = *(const f32x4*)(row + m);
            s += w[0] * hv[m] + w[1] * hv[m + 1] + w[2] * hv[m + 2] + w[3] * hv[m + 3];
        }
        s += __shfl_xor(s, 1); s += __shfl_xor(s, 2);
        if (part == 0) iou[j] = s + b_iouh[j];
    }
    __syncthreads();
    if (tid < 128) {
        float i = iou[tid], o = iou[128 + tid], u = iou[256 + tid];
        float cf = fast_sigmoid(i) * fast_tanh(u) + fc_sum[tid];
        out[tid] = cf;
        hfin[tid] = fast_sigmoid(o) * fast_tanh(cf);
    }
    __syncthreads();
    {
        const float* row = W_lout + jb * 128 + part * 32;
        const float* hv  = hfin + part * 32;
        float s = 0.f;
        #pragma unroll
        for (int m = 0; m < 32; m += 4) {
            f32x4 w = *(const f32x4*)(row + m);
            s += w[0] * hv[m] + w[1] * hv[m + 1] + w[2] * hv[m + 2] + w[3] * hv[m + 3];
        }
        s += __shfl_xor(s, 1); s += __shfl_xor(s, 2);
        if (part == 0) out[128 + jb] = s + b_lout[jb];
    }
}

extern "C" void kernel_launch(void* const* d_in, const int* in_sizes, int n_in,
                              void* d_out, int out_size, void* d_ws, size_t ws_size,
                              hipStream_t stream) {
    const float* numbers = (const float*)d_in[0];
    const float* w_num   = (const float*)d_in[1];
    const float* b_num   = (const float*)d_in[2];
    const float* W_ih    = (const float*)d_in[3];
    const float* W_hh    = (const float*)d_in[4];
    const float* b_ih    = (const float*)d_in[5];
    const float* b_hh    = (const float*)d_in[6];
    const float* W_fh    = (const float*)d_in[7];
    const float* b_fh    = (const float*)d_in[8];
    const float* W_iouh  = (const float*)d_in[9];
    const float* b_iouh  = (const float*)d_in[10];
    const float* W_lout  = (const float*)d_in[11];
    const float* b_lout  = (const float*)d_in[12];
    float* out = (float*)d_out;

    float* ws     = (float*)d_ws;
    float* fc_sum = ws;               // 128
    float* hs_bar = ws + 128;         // 128

    hipMemsetAsync(ws, 0, 256 * sizeof(float), stream);  // fc_sum + hs_bar
    lstm_kernel<<<512, 512, 0, stream>>>(numbers, w_num, b_num, W_ih, W_hh, b_ih, b_hh,
                                         W_fh, b_fh, fc_sum, hs_bar);
    finalize_kernel<<<1, 512, 0, stream>>>(fc_sum, hs_bar, W_iouh, b_iouh,
                                           W_lout, b_lout, out);
}

// Round 13
// 297.190 us; speedup vs baseline: 1.1330x; 1.1330x over previous
//
#include <hip/hip_runtime.h>
#include <math.h>

#define MEM 128
#define HSTR 136   // LDS row stride for h (bf16 elems): 272B, 16B-aligned, bank-balanced
#define LOG2E 1.4426950408889634f

typedef __bf16 bf16x8 __attribute__((ext_vector_type(8)));
typedef __bf16 bf16x4 __attribute__((ext_vector_type(4)));
typedef float  f32x4  __attribute__((ext_vector_type(4)));

__device__ __forceinline__ float fast_rcp(float x) { return __builtin_amdgcn_rcpf(x); }
__device__ __forceinline__ float fast_exp2(float x) { return __builtin_amdgcn_exp2f(x); }
__device__ __forceinline__ float fast_sigmoid(float x) {
    return fast_rcp(1.0f + fast_exp2(-LOG2E * x));
}
__device__ __forceinline__ float fast_tanh(float x) {
    return 2.0f * fast_rcp(1.0f + fast_exp2(-2.0f * LOG2E * x)) - 1.0f;
}

// ============ fused: per-thread prep + 128-step LSTM + partial reduce ============
// v10: v9 (512 overlapping-window blocks, 2 blocks/CU) with the loop's register
// footprint trimmed to fit the 128-unified-VGPR budget of launch_bounds(512,4):
//   - hf[4] removed (final h reloaded from LDS after the loop)
//   - ag/bg kept as packed bf16 (4 regs instead of 8)
// R11 showed the concept drowned in scratch spills (104 MB WRITE_SIZE); this tests
// the 2-barrier-domain hypothesis with spills eliminated.
__global__ __launch_bounds__(512, 4) void lstm_kernel(
        const float* __restrict__ numbers, const float* __restrict__ w_num,
        const float* __restrict__ b_num,   const float* __restrict__ W_ih,
        const float* __restrict__ W_hh,    const float* __restrict__ b_ih,
        const float* __restrict__ b_hh,    const float* __restrict__ W_fh,
        const float* __restrict__ b_fh,
        float* __restrict__ fc_sum, float* __restrict__ hs_bar) {
    __shared__ unsigned short hbuf[2][16 * HSTR];   // h state, bf16, [row][col]
    __shared__ float xls[128 * 16];                 // normalized x, [t][row]
    __shared__ float mean_l[100], inv_l[100];

    const int tid  = threadIdx.x;
    const int lane = tid & 63;
    const int wave = tid >> 6;        // 0..7 -> gate-column group
    const int quad = lane >> 4;       // 0..3
    const int lcol = lane & 15;
    const int m0   = wave * 16;       // column offset within a gate (0..112)
    const int r0   = blockIdx.x * 8;  // overlapping window: rows r0..r0+15 (mod 4096)

    // ---- stats LUT (redundant per block, register/LDS only) ----
    if (tid < 100) xls[tid] = numbers[tid];   // stage first 100 numbers
    __syncthreads();
    if (tid < 100) {
        float s = 0.f, ss = 0.f;
        for (int j = 0; j <= tid; ++j) { float v = xls[j]; s += v; ss += v * v; }
        float cap  = (float)(tid + 1);
        float mean = s / cap;
        float var  = ss / cap - mean * mean;
        if (var < 0.f) var = 0.f;
        float sd = sqrtf(var);
        float inv = (cap > 3.0f && sd > 1e-8f) ? (1.0f / sd) : 1.0f;
        mean_l[tid] = mean;
        inv_l[tid]  = inv;
    }
    __syncthreads();

    // gate pre-scales: sigmoid gates -log2e, tanh gate -2*log2e, folded into weights
    const float GS[4] = { -LOG2E, -LOG2E, -2.0f * LOG2E, -LOG2E };

    // ---- per-thread rank-1 coefficients via quad-split dots (packed bf16) ----
    bf16x4 agh, bgh;
    #pragma unroll
    for (int g = 0; g < 4; ++g) {
        int j = g * 128 + m0 + lcol;
        const float* row = W_ih + j * 256 + 128 + quad * 32;
        const float* wn  = w_num + quad * 32;
        const float* bn  = b_num + quad * 32;
        float a = 0.f, b = 0.f;
        #pragma unroll
        for (int m = 0; m < 32; m += 4) {
            f32x4 w  = *(const f32x4*)(row + m);
            f32x4 vn = *(const f32x4*)(wn + m);
            f32x4 vb = *(const f32x4*)(bn + m);
            a += w[0] * vn[0] + w[1] * vn[1] + w[2] * vn[2] + w[3] * vn[3];
            b += w[0] * vb[0] + w[1] * vb[1] + w[2] * vb[2] + w[3] * vb[3];
        }
        a += __shfl_xor(a, 16); a += __shfl_xor(a, 32);
        b += __shfl_xor(b, 16); b += __shfl_xor(b, 32);
        agh[g] = (__bf16)(a * GS[g]);
        bgh[g] = (__bf16)((b + b_ih[j] + b_hh[j]) * GS[g]);
    }

    // ---- load + normalize x into LDS [t][row] (rows wrap mod 4096) ----
    for (int i = tid; i < 16 * 128; i += 512) {
        int row = i >> 7;
        int t   = i & 127;
        int flat = (((r0 + row) & 4095) * 128) + t;
        int ii = (flat < 100) ? flat : 99;   // k>100 uses stats at k=100
        float v = numbers[flat];
        xls[t * 16 + row] = (v - mean_l[ii]) * inv_l[ii];
    }
    // ---- zero h buffer 0 (h0 = 0) ----
    for (int i = tid; i < 16 * HSTR; i += 512) hbuf[0][i] = 0;

    // ---- persistent W_hh B-fragments (bf16, pre-scaled) in registers: [gate][kk] ----
    bf16x8 bf[4][4];
    #pragma unroll
    for (int g = 0; g < 4; ++g) {
        #pragma unroll
        for (int kk = 0; kk < 4; ++kk) {
            int j = g * 128 + m0 + lcol;            // gate output column (n)
            const float* p = W_hh + j * 128 + kk * 32 + quad * 8;
            f32x4 w0 = *(const f32x4*)p;
            f32x4 w1 = *(const f32x4*)(p + 4);
            bf16x8 bt;
            #pragma unroll
            for (int q = 0; q < 4; ++q) {
                bt[q]     = (__bf16)(w0[q] * GS[g]);
                bt[q + 4] = (__bf16)(w1[q] * GS[g]);
            }
            bf[g][kk] = bt;
        }
    }

    float c[4]  = {0.f, 0.f, 0.f, 0.f};  // C-layout: row = quad*4+r, col = m0+lcol
    __syncthreads();

    // ---------------- 128-step LSTM ----------------
    auto step = [&](int t, const unsigned short* hin, unsigned short* hout) {
        bf16x8 af[4];
        #pragma unroll
        for (int kk = 0; kk < 4; ++kk)
            af[kk] = *(const bf16x8*)(const void*)(hin + lcol * HSTR + kk * 32 + quad * 8);
        f32x4 xq = *(const f32x4*)(const void*)(xls + t * 16 + quad * 4);
        f32x4 acc[4];
        #pragma unroll
        for (int g = 0; g < 4; ++g) {
            float agf = (float)agh[g];
            float bgf = (float)bgh[g];
            f32x4 a0;
            #pragma unroll
            for (int r = 0; r < 4; ++r) a0[r] = xq[r] * agf + bgf;
            #pragma unroll
            for (int kk = 0; kk < 4; ++kk)
                a0 = __builtin_amdgcn_mfma_f32_16x16x32_bf16(af[kk], bf[g][kk], a0, 0, 0, 0);
            acc[g] = a0;
        }
        // gate math (5 exp2 + 2 rcp): acc0/1/3 = -log2e*(i,f,o); acc2 = -2log2e*g
        // c2 = [c*(1+ei)(1+eg) + (1-eg)(1+ef)] / [(1+ef)(1+ei)(1+eg)]
        // h  = (1-ec)/((1+eo)(1+ec)),  ec = 2^(-2*log2e*c2)
        #pragma unroll
        for (int r = 0; r < 4; ++r) {
            float ei = fast_exp2(acc[0][r]);
            float ef = fast_exp2(acc[1][r]);
            float eg = fast_exp2(acc[2][r]);
            float eo = fast_exp2(acc[3][r]);
            float p  = (1.0f + ei) * (1.0f + eg);
            float df = 1.0f + ef;
            float rq = fast_rcp(df * p);
            float c2 = (c[r] * p + (1.0f - eg) * df) * rq;
            c[r] = c2;
            float ec  = fast_exp2(-2.0f * LOG2E * c2);
            float roc = fast_rcp((1.0f + eo) * (1.0f + ec));
            float h   = (1.0f - ec) * roc;                      // so*tanh(c2)
            hout[(quad * 4 + r) * HSTR + m0 + lcol] = __builtin_bit_cast(unsigned short, (__bf16)h);
        }
        __syncthreads();
    };

    for (int t = 0; t < 128; t += 2) {
        step(t,     hbuf[0], hbuf[1]);
        step(t + 1, hbuf[1], hbuf[0]);
    }
    // final h (t=127, bf16) lives in hbuf[0]; final c in regs

    // ---- hs_bar partial (x0.5: each row is covered by exactly 2 blocks) ----
    float v = 0.f;
    #pragma unroll
    for (int r = 0; r < 4; ++r) {
        unsigned short u = hbuf[0][(quad * 4 + r) * HSTR + m0 + lcol];
        v += (float)__builtin_bit_cast(__bf16, u);
    }
    v += __shfl_xor(v, 16);
    v += __shfl_xor(v, 32);
    if (lane < 16) atomicAdd(&hs_bar[m0 + lane], 0.5f * v);

    // ---- f_g = sigmoid(h @ W_fh^T + b_fh); fc partial = sum_rows f_g*c ----
    f32x4 facc;
    {
        float bb = b_fh[m0 + lcol];
        #pragma unroll
        for (int r = 0; r < 4; ++r) facc[r] = bb;
    }
    #pragma unroll
    for (int kk = 0; kk < 4; ++kk) {
        bf16x8 afr = *(const bf16x8*)(const void*)(hbuf[0] + lcol * HSTR + kk * 32 + quad * 8);
        const float* p = W_fh + (m0 + lcol) * 128 + kk * 32 + quad * 8;
        f32x4 w0 = *(const f32x4*)p;
        f32x4 w1 = *(const f32x4*)(p + 4);
        bf16x8 wt;
        #pragma unroll
        for (int q = 0; q < 4; ++q) { wt[q] = (__bf16)w0[q]; wt[q + 4] = (__bf16)w1[q]; }
        facc = __builtin_amdgcn_mfma_f32_16x16x32_bf16(afr, wt, facc, 0, 0, 0);
    }
    float fcv = 0.f;
    #pragma unroll
    for (int r = 0; r < 4; ++r) fcv += fast_sigmoid(facc[r]) * c[r];
    fcv += __shfl_xor(fcv, 16);
    fcv += __shfl_xor(fcv, 32);
    if (lane < 16) atomicAdd(&fc_sum[m0 + lane], 0.5f * fcv);
}

// ---------------- epilogue: root Tree-LSTM cell + output projection ----------------
__global__ void finalize_kernel(const float* __restrict__ fc_sum,
                                const float* __restrict__ hs_bar,
                                const float* __restrict__ W_iouh,
                                const float* __restrict__ b_iouh,
                                const float* __restrict__ W_lout,
                                const float* __restrict__ b_lout,
                                float* __restrict__ out) {
    __shared__ float hsb[128], iou[384], hfin[128];
    int tid = threadIdx.x;            // 512
    const int part = tid & 3;         // 0..3
    const int jb   = tid >> 2;        // 0..127
    if (tid < 128) hsb[tid] = hs_bar[tid];
    __syncthreads();
    #pragma unroll
    for (int round = 0; round < 3; ++round) {
        int j = jb + round * 128;
        const float* row = W_iouh + j * 128 + part * 32;
        const float* hv  = hsb + part * 32;
        float s = 0.f;
        #pragma unroll
        for (int m = 0; m < 32; m += 4) {
            f32x4 w = *(const f32x4*)(row + m);
            s += w[0] * hv[m] + w[1] * hv[m + 1] + w[2] * hv[m + 2] + w[3] * hv[m + 3];
        }
        s += __shfl_xor(s, 1); s += __shfl_xor(s, 2);
        if (part == 0) iou[j] = s + b_iouh[j];
    }
    __syncthreads();
    if (tid < 128) {
        float i = iou[tid], o = iou[128 + tid], u = iou[256 + tid];
        float cf = fast_sigmoid(i) * fast_tanh(u) + fc_sum[tid];
        out[tid] = cf;
        hfin[tid] = fast_sigmoid(o) * fast_tanh(cf);
    }
    __syncthreads();
    {
        const float* row = W_lout + jb * 128 + part * 32;
        const float* hv  = hfin + part * 32;
        float s = 0.f;
        #pragma unroll
        for (int m = 0; m < 32; m += 4) {
            f32x4 w = *(const f32x4*)(row + m);
            s += w[0] * hv[m] + w[1] * hv[m + 1] + w[2] * hv[m + 2] + w[3] * hv[m + 3];
        }
        s += __shfl_xor(s, 1); s += __shfl_xor(s, 2);
        if (part == 0) out[128 + jb] = s + b_lout[jb];
    }
}

extern "C" void kernel_launch(void* const* d_in, const int* in_sizes, int n_in,
                              void* d_out, int out_size, void* d_ws, size_t ws_size,
                              hipStream_t stream) {
    const float* numbers = (const float*)d_in[0];
    const float* w_num   = (const float*)d_in[1];
    const float* b_num   = (const float*)d_in[2];
    const float* W_ih    = (const float*)d_in[3];
    const float* W_hh    = (const float*)d_in[4];
    const float* b_ih    = (const float*)d_in[5];
    const float* b_hh    = (const float*)d_in[6];
    const float* W_fh    = (const float*)d_in[7];
    const float* b_fh    = (const float*)d_in[8];
    const float* W_iouh  = (const float*)d_in[9];
    const float* b_iouh  = (const float*)d_in[10];
    const float* W_lout  = (const float*)d_in[11];
    const float* b_lout  = (const float*)d_in[12];
    float* out = (float*)d_out;

    float* ws     = (float*)d_ws;
    float* fc_sum = ws;               // 128
    float* hs_bar = ws + 128;         // 128

    hipMemsetAsync(ws, 0, 256 * sizeof(float), stream);  // fc_sum + hs_bar
    lstm_kernel<<<512, 512, 0, stream>>>(numbers, w_num, b_num, W_ih, W_hh, b_ih, b_hh,
                                         W_fh, b_fh, fc_sum, hs_bar);
    finalize_kernel<<<1, 512, 0, stream>>>(fc_sum, hs_bar, W_iouh, b_iouh,
                                           W_lout, b_lout, out);
}

// Round 14
// 212.381 us; speedup vs baseline: 1.5854x; 1.3993x over previous
//
#include <hip/hip_runtime.h>
#include <math.h>

#define MEM 128
#define HSTR 136   // LDS row stride for h (bf16 elems): 272B, 16B-aligned, bank-balanced
#define LOG2E 1.4426950408889634f

typedef __bf16 bf16x8 __attribute__((ext_vector_type(8)));
typedef float  f32x4  __attribute__((ext_vector_type(4)));

__device__ __forceinline__ float fast_rcp(float x) { return __builtin_amdgcn_rcpf(x); }
__device__ __forceinline__ float fast_exp2(float x) { return __builtin_amdgcn_exp2f(x); }
__device__ __forceinline__ float fast_sigmoid(float x) {
    return fast_rcp(1.0f + fast_exp2(-LOG2E * x));
}
__device__ __forceinline__ float fast_tanh(float x) {
    return 2.0f * fast_rcp(1.0f + fast_exp2(-2.0f * LOG2E * x)) - 1.0f;
}

// ============ fused: per-thread prep + 128-step LSTM + partial reduce ============
// MEASURED-BEST configuration (R8: lstm 140.3-142.0 us, total 214.95 us, absmax 1.0):
// 256 blocks x 512 threads, 1 block/CU (launch_bounds(512,2) -> 256-VGPR budget, no
// spill), f32 rank-1 coefficients, merged-reciprocal gate math (5 exp2 + 2 rcp).
// R11/R13 established that 2 blocks/CU (any 128-VGPR-budget variant) spills the
// ~115-register loop working set and regresses 1.7-2x; this config is the floor.
__global__ __launch_bounds__(512, 2) void lstm_kernel(
        const float* __restrict__ numbers, const float* __restrict__ w_num,
        const float* __restrict__ b_num,   const float* __restrict__ W_ih,
        const float* __restrict__ W_hh,    const float* __restrict__ b_ih,
        const float* __restrict__ b_hh,    const float* __restrict__ W_fh,
        const float* __restrict__ b_fh,
        float* __restrict__ fc_sum, float* __restrict__ hs_bar) {
    __shared__ unsigned short hbuf[2][16 * HSTR];   // h state, bf16, [row][col]
    __shared__ float xls[128 * 16];                 // normalized x, [t][row]
    __shared__ float mean_l[100], inv_l[100];

    const int tid  = threadIdx.x;
    const int lane = tid & 63;
    const int wave = tid >> 6;        // 0..7 -> gate-column group
    const int quad = lane >> 4;       // 0..3
    const int lcol = lane & 15;
    const int m0   = wave * 16;       // column offset within a gate (0..112)
    const int r0   = blockIdx.x * 16; // global batch row base

    // ---- stats LUT (redundant per block, register/LDS only) ----
    if (tid < 100) xls[tid] = numbers[tid];   // stage first 100 numbers
    __syncthreads();
    if (tid < 100) {
        float s = 0.f, ss = 0.f;
        for (int j = 0; j <= tid; ++j) { float v = xls[j]; s += v; ss += v * v; }
        float cap  = (float)(tid + 1);
        float mean = s / cap;
        float var  = ss / cap - mean * mean;
        if (var < 0.f) var = 0.f;
        float sd = sqrtf(var);
        float inv = (cap > 3.0f && sd > 1e-8f) ? (1.0f / sd) : 1.0f;
        mean_l[tid] = mean;
        inv_l[tid]  = inv;
    }
    __syncthreads();

    // gate pre-scales: sigmoid gates -log2e, tanh gate -2*log2e, folded into weights
    const float GS[4] = { -LOG2E, -LOG2E, -2.0f * LOG2E, -LOG2E };

    // ---- per-thread rank-1 coefficients via quad-split dots (no LDS, no barrier) ----
    float ag[4], bg[4];
    #pragma unroll
    for (int g = 0; g < 4; ++g) {
        int j = g * 128 + m0 + lcol;
        const float* row = W_ih + j * 256 + 128 + quad * 32;
        const float* wn  = w_num + quad * 32;
        const float* bn  = b_num + quad * 32;
        float a = 0.f, b = 0.f;
        #pragma unroll
        for (int m = 0; m < 32; m += 4) {
            f32x4 w  = *(const f32x4*)(row + m);
            f32x4 vn = *(const f32x4*)(wn + m);
            f32x4 vb = *(const f32x4*)(bn + m);
            a += w[0] * vn[0] + w[1] * vn[1] + w[2] * vn[2] + w[3] * vn[3];
            b += w[0] * vb[0] + w[1] * vb[1] + w[2] * vb[2] + w[3] * vb[3];
        }
        a += __shfl_xor(a, 16); a += __shfl_xor(a, 32);
        b += __shfl_xor(b, 16); b += __shfl_xor(b, 32);
        ag[g] = a * GS[g];
        bg[g] = (b + b_ih[j] + b_hh[j]) * GS[g];
    }

    // ---- load + normalize x into LDS [t][row] ----
    for (int i = tid; i < 16 * 128; i += 512) {
        int row = i >> 7;
        int t   = i & 127;
        int flat = (r0 + row) * 128 + t;
        int ii = (flat < 100) ? flat : 99;   // k>100 uses stats at k=100
        float v = numbers[flat];
        xls[t * 16 + row] = (v - mean_l[ii]) * inv_l[ii];
    }
    // ---- zero h buffer 0 (h0 = 0) ----
    for (int i = tid; i < 16 * HSTR; i += 512) hbuf[0][i] = 0;

    // ---- persistent W_hh B-fragments (bf16, pre-scaled) in registers: [gate][kk] ----
    bf16x8 bf[4][4];
    #pragma unroll
    for (int g = 0; g < 4; ++g) {
        #pragma unroll
        for (int kk = 0; kk < 4; ++kk) {
            int j = g * 128 + m0 + lcol;            // gate output column (n)
            const float* p = W_hh + j * 128 + kk * 32 + quad * 8;
            f32x4 w0 = *(const f32x4*)p;
            f32x4 w1 = *(const f32x4*)(p + 4);
            bf16x8 bt;
            #pragma unroll
            for (int q = 0; q < 4; ++q) {
                bt[q]     = (__bf16)(w0[q] * GS[g]);
                bt[q + 4] = (__bf16)(w1[q] * GS[g]);
            }
            bf[g][kk] = bt;
        }
    }

    float c[4]  = {0.f, 0.f, 0.f, 0.f};  // C-layout: row = quad*4+r, col = m0+lcol
    float hf[4] = {0.f, 0.f, 0.f, 0.f};
    __syncthreads();

    // ---------------- 128-step LSTM ----------------
    auto step = [&](int t, const unsigned short* hin, unsigned short* hout) {
        bf16x8 af[4];
        #pragma unroll
        for (int kk = 0; kk < 4; ++kk)
            af[kk] = *(const bf16x8*)(const void*)(hin + lcol * HSTR + kk * 32 + quad * 8);
        f32x4 xq = *(const f32x4*)(const void*)(xls + t * 16 + quad * 4);
        f32x4 acc[4];
        #pragma unroll
        for (int g = 0; g < 4; ++g) {
            f32x4 a0;
            #pragma unroll
            for (int r = 0; r < 4; ++r) a0[r] = xq[r] * ag[g] + bg[g];
            #pragma unroll
            for (int kk = 0; kk < 4; ++kk)
                a0 = __builtin_amdgcn_mfma_f32_16x16x32_bf16(af[kk], bf[g][kk], a0, 0, 0, 0);
            acc[g] = a0;
        }
        // gate math (merged-rcp form): acc0/1/3 = -log2e*(i,f,o); acc2 = -2log2e*g
        // si*tanh(g) = (1-eg)/((1+ei)(1+eg));  so*tanh(c2) = (1-ec)/((1+eo)(1+ec))
        #pragma unroll
        for (int r = 0; r < 4; ++r) {
            float ei = fast_exp2(acc[0][r]);
            float ef = fast_exp2(acc[1][r]);
            float eg = fast_exp2(acc[2][r]);
            float eo = fast_exp2(acc[3][r]);
            float rf  = fast_rcp(1.0f + ef);                    // sigmoid(f)
            float rig = fast_rcp((1.0f + ei) * (1.0f + eg));
            float c2  = c[r] * rf + (1.0f - eg) * rig;          // sf*c + si*tanh(g)
            c[r] = c2;
            float ec  = fast_exp2(-2.0f * LOG2E * c2);
            float roc = fast_rcp((1.0f + eo) * (1.0f + ec));
            float h   = (1.0f - ec) * roc;                      // so*tanh(c2)
            hf[r] = h;
            hout[(quad * 4 + r) * HSTR + m0 + lcol] = __builtin_bit_cast(unsigned short, (__bf16)h);
        }
        __syncthreads();
    };

    for (int t = 0; t < 128; t += 2) {
        step(t,     hbuf[0], hbuf[1]);
        step(t + 1, hbuf[1], hbuf[0]);
    }
    // final h (t=127) lives in hbuf[0]; final c in regs; hf = final h (fp32)

    // ---- hs_bar partial: sum over this block's 16 rows ----
    float v = hf[0] + hf[1] + hf[2] + hf[3];
    v += __shfl_xor(v, 16);
    v += __shfl_xor(v, 32);
    if (lane < 16) atomicAdd(&hs_bar[m0 + lane], v);

    // ---- f_g = sigmoid(h @ W_fh^T + b_fh); fc partial = sum_rows f_g*c ----
    f32x4 facc;
    {
        float bb = b_fh[m0 + lcol];
        #pragma unroll
        for (int r = 0; r < 4; ++r) facc[r] = bb;
    }
    #pragma unroll
    for (int kk = 0; kk < 4; ++kk) {
        bf16x8 afr = *(const bf16x8*)(const void*)(hbuf[0] + lcol * HSTR + kk * 32 + quad * 8);
        const float* p = W_fh + (m0 + lcol) * 128 + kk * 32 + quad * 8;
        f32x4 w0 = *(const f32x4*)p;
        f32x4 w1 = *(const f32x4*)(p + 4);
        bf16x8 wt;
        #pragma unroll
        for (int q = 0; q < 4; ++q) { wt[q] = (__bf16)w0[q]; wt[q + 4] = (__bf16)w1[q]; }
        facc = __builtin_amdgcn_mfma_f32_16x16x32_bf16(afr, wt, facc, 0, 0, 0);
    }
    float fcv = 0.f;
    #pragma unroll
    for (int r = 0; r < 4; ++r) fcv += fast_sigmoid(facc[r]) * c[r];
    fcv += __shfl_xor(fcv, 16);
    fcv += __shfl_xor(fcv, 32);
    if (lane < 16) atomicAdd(&fc_sum[m0 + lane], fcv);
}

// ---------------- epilogue: root Tree-LSTM cell + output projection ----------------
__global__ void finalize_kernel(const float* __restrict__ fc_sum,
                                const float* __restrict__ hs_bar,
                                const float* __restrict__ W_iouh,
                                const float* __restrict__ b_iouh,
                                const float* __restrict__ W_lout,
                                const float* __restrict__ b_lout,
                                float* __restrict__ out) {
    __shared__ float hsb[128], iou[384], hfin[128];
    int tid = threadIdx.x;            // 512
    const int part = tid & 3;         // 0..3
    const int jb   = tid >> 2;        // 0..127
    if (tid < 128) hsb[tid] = hs_bar[tid];
    __syncthreads();
    #pragma unroll
    for (int round = 0; round < 3; ++round) {
        int j = jb + round * 128;
        const float* row = W_iouh + j * 128 + part * 32;
        const float* hv  = hsb + part * 32;
        float s = 0.f;
        #pragma unroll
        for (int m = 0; m < 32; m += 4) {
            f32x4 w = *(const f32x4*)(row + m);
            s += w[0] * hv[m] + w[1] * hv[m + 1] + w[2] * hv[m + 2] + w[3] * hv[m + 3];
        }
        s += __shfl_xor(s, 1); s += __shfl_xor(s, 2);
        if (part == 0) iou[j] = s + b_iouh[j];
    }
    __syncthreads();
    if (tid < 128) {
        float i = iou[tid], o = iou[128 + tid], u = iou[256 + tid];
        float cf = fast_sigmoid(i) * fast_tanh(u) + fc_sum[tid];
        out[tid] = cf;
        hfin[tid] = fast_sigmoid(o) * fast_tanh(cf);
    }
    __syncthreads();
    {
        const float* row = W_lout + jb * 128 + part * 32;
        const float* hv  = hfin + part * 32;
        float s = 0.f;
        #pragma unroll
        for (int m = 0; m < 32; m += 4) {
            f32x4 w = *(const f32x4*)(row + m);
            s += w[0] * hv[m] + w[1] * hv[m + 1] + w[2] * hv[m + 2] + w[3] * hv[m + 3];
        }
        s += __shfl_xor(s, 1); s += __shfl_xor(s, 2);
        if (part == 0) out[128 + jb] = s + b_lout[jb];
    }
}

extern "C" void kernel_launch(void* const* d_in, const int* in_sizes, int n_in,
                              void* d_out, int out_size, void* d_ws, size_t ws_size,
                              hipStream_t stream) {
    const float* numbers = (const float*)d_in[0];
    const float* w_num   = (const float*)d_in[1];
    const float* b_num   = (const float*)d_in[2];
    const float* W_ih    = (const float*)d_in[3];
    const float* W_hh    = (const float*)d_in[4];
    const float* b_ih    = (const float*)d_in[5];
    const float* b_hh    = (const float*)d_in[6];
    const float* W_fh    = (const float*)d_in[7];
    const float* b_fh    = (const float*)d_in[8];
    const float* W_iouh  = (const float*)d_in[9];
    const float* b_iouh  = (const float*)d_in[10];
    const float* W_lout  = (const float*)d_in[11];
    const float* b_lout  = (const float*)d_in[12];
    float* out = (float*)d_out;

    float* ws     = (float*)d_ws;
    float* fc_sum = ws;               // 128
    float* hs_bar = ws + 128;         // 128

    hipMemsetAsync(ws, 0, 256 * sizeof(float), stream);  // fc_sum + hs_bar
    lstm_kernel<<<256, 512, 0, stream>>>(numbers, w_num, b_num, W_ih, W_hh, b_ih, b_hh,
                                         W_fh, b_fh, fc_sum, hs_bar);
    finalize_kernel<<<1, 512, 0, stream>>>(fc_sum, hs_bar, W_iouh, b_iouh,
                                           W_lout, b_lout, out);
}